// Round 1
// baseline (25.030 us; speedup 1.0000x reference)
//
#include <hip/hip_runtime.h>

#define VOCAB  100000
#define EMBED  128
#define BATCH  64
#define SEQLEN 2048

// ---------------------------------------------------------------------------
// Kernel 1: per-batch partial embedding sums.
// grid.x = BATCH * split, block = 128 threads.
// Block (b, s) sums `chunk` consecutive tokens of batch b into
// partial[b][s][0..127]  (deterministic, no atomics).
// Thread layout: c = tid & 31 -> float4 slice of a row (32 lanes * 16B = 512B
// coalesced), r = tid >> 5 -> which row of a 4-row group per iteration.
// ---------------------------------------------------------------------------
__global__ __launch_bounds__(128) void cbow_partial_kernel(
    const int* __restrict__ x, const float* __restrict__ emb,
    float* __restrict__ partial, int split, int chunk) {
    const int blk = blockIdx.x;
    const int b = blk / split;
    const int s = blk - b * split;
    const int tid = threadIdx.x;
    const int c = tid & 31;   // float4 column group within the 128-float row
    const int r = tid >> 5;   // row group 0..3

    __shared__ int toks[SEQLEN];  // max chunk (split=1 fallback); 8 KiB
    const int base = b * SEQLEN + s * chunk;
    for (int i = tid; i < chunk; i += 128) toks[i] = x[base + i];
    __syncthreads();

    float4 acc = make_float4(0.f, 0.f, 0.f, 0.f);
#pragma unroll 4
    for (int i = r; i < chunk; i += 4) {
        const float4 v =
            *reinterpret_cast<const float4*>(&emb[(size_t)toks[i] * EMBED + c * 4]);
        acc.x += v.x;
        acc.y += v.y;
        acc.z += v.z;
        acc.w += v.w;
    }

    __shared__ float psum[4][EMBED];
    psum[r][c * 4 + 0] = acc.x;
    psum[r][c * 4 + 1] = acc.y;
    psum[r][c * 4 + 2] = acc.z;
    psum[r][c * 4 + 3] = acc.w;
    __syncthreads();

    // 128 threads: element e = tid, sum 4 row-group partials.
    const float ssum = psum[0][tid] + psum[1][tid] + psum[2][tid] + psum[3][tid];
    partial[((size_t)b * split + s) * EMBED + tid] = ssum;
}

// ---------------------------------------------------------------------------
// Kernel 2: reduce partials over `split` and apply boundary corrections.
// grid.x = BATCH, block = 128 threads (one per embedding element).
// Output layout: out[b][o][e], o in {(-1), (-2), (+1), (+2)} per the
// reference's offsets = concat(-arange(1,C+1), arange(1,C+1)).
// ---------------------------------------------------------------------------
__global__ __launch_bounds__(128) void cbow_final_kernel(
    const int* __restrict__ x, const float* __restrict__ emb,
    const float* __restrict__ partial, float* __restrict__ out, int split) {
    const int b = blockIdx.x;
    const int e = threadIdx.x;

    float S = 0.f;
    for (int s = 0; s < split; ++s)
        S += partial[((size_t)b * split + s) * EMBED + e];

    const float e0 = emb[e];  // emb[token 0]
    const int t0  = x[b * SEQLEN + 0];
    const int t1  = x[b * SEQLEN + 1];
    const int tl2 = x[b * SEQLEN + SEQLEN - 2];
    const int tl1 = x[b * SEQLEN + SEQLEN - 1];
    const float v0  = emb[(size_t)t0  * EMBED + e];
    const float v1  = emb[(size_t)t1  * EMBED + e];
    const float vl2 = emb[(size_t)tl2 * EMBED + e];
    const float vl1 = emb[(size_t)tl1 * EMBED + e];

    float* ob = out + (size_t)b * 4 * EMBED;
    ob[0 * EMBED + e] = S - vl1 + e0;              // offset -1: idx 0..L-2, 1 OOB
    ob[1 * EMBED + e] = S - vl2 - vl1 + 2.f * e0;  // offset -2: idx 0..L-3, 2 OOB
    ob[2 * EMBED + e] = S - v0 + e0;               // offset +1: idx 1..L-1, 1 OOB
    ob[3 * EMBED + e] = S - v0 - v1 + 2.f * e0;    // offset +2: idx 2..L-1, 2 OOB
}

extern "C" void kernel_launch(void* const* d_in, const int* in_sizes, int n_in,
                              void* d_out, int out_size, void* d_ws, size_t ws_size,
                              hipStream_t stream) {
    const int*   x   = (const int*)d_in[0];
    const float* emb = (const float*)d_in[1];
    float*       out = (float*)d_out;
    float*       ws  = (float*)d_ws;

    // Pick largest power-of-2 split whose partial buffer fits in d_ws.
    int split = 32;
    while (split > 1 &&
           (size_t)BATCH * split * EMBED * sizeof(float) > ws_size)
        split >>= 1;
    const int chunk = SEQLEN / split;

    cbow_partial_kernel<<<dim3(BATCH * split), dim3(128), 0, stream>>>(
        x, emb, ws, split, chunk);
    cbow_final_kernel<<<dim3(BATCH), dim3(128), 0, stream>>>(
        x, emb, ws, out, split);
}

// Round 2
// 18.639 us; speedup vs baseline: 1.3429x; 1.3429x over previous
//
#include <hip/hip_runtime.h>

#define VOCAB  100000
#define EMBED  128
#define BATCH  64
#define SEQLEN 2048

// ---------------------------------------------------------------------------
// Kernel 1: per-batch partial embedding sums.
// grid.x = BATCH * SPLIT, block = 128 threads.
// Block (b, s) sums CHUNK consecutive tokens of batch b into partial[b][s][:].
// Thread layout: c = tid & 31 -> float4 slice of a row (32 lanes * 16B = 512B
// fully coalesced), r = tid >> 5 -> which row of each 4-row group.
// CHUNK compile-time so the gather loop fully unrolls (CHUNK/4 loads in
// flight per thread before the first vmcnt wait).
// ---------------------------------------------------------------------------
template <int CHUNK>
__global__ __launch_bounds__(128) void cbow_partial_kernel(
    const int* __restrict__ x, const float* __restrict__ emb,
    float* __restrict__ partial) {
    constexpr int SPLIT = SEQLEN / CHUNK;
    const int blk = blockIdx.x;
    const int b = blk / SPLIT;
    const int s = blk - b * SPLIT;
    const int tid = threadIdx.x;
    const int c = tid & 31;   // float4 column within the 128-float row
    const int r = tid >> 5;   // row group 0..3

    __shared__ int toks[CHUNK];
    const int base = b * SEQLEN + s * CHUNK;
    for (int i = tid; i < CHUNK; i += 128) toks[i] = x[base + i];
    __syncthreads();

    constexpr int ITERS = CHUNK / 4;  // loads per thread
    float4 a0 = make_float4(0.f, 0.f, 0.f, 0.f);
    float4 a1 = make_float4(0.f, 0.f, 0.f, 0.f);
#pragma unroll
    for (int it = 0; it < ITERS; it += 2) {
        const float4 v0 = *reinterpret_cast<const float4*>(
            &emb[(size_t)toks[r + 4 * it] * EMBED + c * 4]);
        const float4 v1 = *reinterpret_cast<const float4*>(
            &emb[(size_t)toks[r + 4 * (it + 1)] * EMBED + c * 4]);
        a0.x += v0.x; a0.y += v0.y; a0.z += v0.z; a0.w += v0.w;
        a1.x += v1.x; a1.y += v1.y; a1.z += v1.z; a1.w += v1.w;
    }
    a0.x += a1.x; a0.y += a1.y; a0.z += a1.z; a0.w += a1.w;

    __shared__ float psum[4][EMBED];
    psum[r][c * 4 + 0] = a0.x;
    psum[r][c * 4 + 1] = a0.y;
    psum[r][c * 4 + 2] = a0.z;
    psum[r][c * 4 + 3] = a0.w;
    __syncthreads();

    const float ssum = psum[0][tid] + psum[1][tid] + psum[2][tid] + psum[3][tid];
    partial[((size_t)b * SPLIT + s) * EMBED + tid] = ssum;
}

// ---------------------------------------------------------------------------
// Kernel 2: reduce partials over `split` and apply boundary corrections.
// grid.x = BATCH, block = 256 (two 128-thread groups each sum half the
// splits; LDS combine). Output out[b][o][e], o = {-1,-2,+1,+2}.
// ---------------------------------------------------------------------------
__global__ __launch_bounds__(256) void cbow_final_kernel(
    const int* __restrict__ x, const float* __restrict__ emb,
    const float* __restrict__ partial, float* __restrict__ out, int split) {
    const int b = blockIdx.x;
    const int e = threadIdx.x & 127;
    const int g = threadIdx.x >> 7;
    const int half = split >> 1;  // split is always even (>= 2)

    float S = 0.f;
    const float* p = partial + ((size_t)b * split + (size_t)g * half) * EMBED + e;
#pragma unroll 8
    for (int s = 0; s < half; ++s) S += p[(size_t)s * EMBED];

    __shared__ float sh[EMBED];
    if (g == 1) sh[e] = S;
    __syncthreads();
    if (g == 0) {
        S += sh[e];

        const float e0 = emb[e];  // emb[token 0]
        const int t0  = x[b * SEQLEN + 0];
        const int t1  = x[b * SEQLEN + 1];
        const int tl2 = x[b * SEQLEN + SEQLEN - 2];
        const int tl1 = x[b * SEQLEN + SEQLEN - 1];
        const float v0  = emb[(size_t)t0  * EMBED + e];
        const float v1  = emb[(size_t)t1  * EMBED + e];
        const float vl2 = emb[(size_t)tl2 * EMBED + e];
        const float vl1 = emb[(size_t)tl1 * EMBED + e];

        float* ob = out + (size_t)b * 4 * EMBED;
        ob[0 * EMBED + e] = S - vl1 + e0;              // offset -1
        ob[1 * EMBED + e] = S - vl2 - vl1 + 2.f * e0;  // offset -2
        ob[2 * EMBED + e] = S - v0 + e0;               // offset +1
        ob[3 * EMBED + e] = S - v0 - v1 + 2.f * e0;    // offset +2
    }
}

extern "C" void kernel_launch(void* const* d_in, const int* in_sizes, int n_in,
                              void* d_out, int out_size, void* d_ws, size_t ws_size,
                              hipStream_t stream) {
    const int*   x   = (const int*)d_in[0];
    const float* emb = (const float*)d_in[1];
    float*       out = (float*)d_out;
    float*       ws  = (float*)d_ws;

    // Largest power-of-2 split (>=2) whose partial buffer fits in d_ws.
    int split = 64;
    while (split > 2 &&
           (size_t)BATCH * split * EMBED * sizeof(float) > ws_size)
        split >>= 1;

    switch (split) {
        case 64:
            cbow_partial_kernel<32><<<dim3(BATCH * 64), dim3(128), 0, stream>>>(x, emb, ws);
            break;
        case 32:
            cbow_partial_kernel<64><<<dim3(BATCH * 32), dim3(128), 0, stream>>>(x, emb, ws);
            break;
        case 16:
            cbow_partial_kernel<128><<<dim3(BATCH * 16), dim3(128), 0, stream>>>(x, emb, ws);
            break;
        case 8:
            cbow_partial_kernel<256><<<dim3(BATCH * 8), dim3(128), 0, stream>>>(x, emb, ws);
            break;
        case 4:
            cbow_partial_kernel<512><<<dim3(BATCH * 4), dim3(128), 0, stream>>>(x, emb, ws);
            break;
        default:
            cbow_partial_kernel<1024><<<dim3(BATCH * 2), dim3(128), 0, stream>>>(x, emb, ws);
            break;
    }
    cbow_final_kernel<<<dim3(BATCH), dim3(256), 0, stream>>>(x, emb, ws, out, split);
}